// Round 1
// baseline (817.042 us; speedup 1.0000x reference)
//
#include <hip/hip_runtime.h>
#include <hip/hip_bf16.h>

#define NTOK 4096
#define DM   1024
#define DF   4096
#define ROWS_TOTAL 12288   // 4096 shared + 8192 routed (top-2)
#define BM 128
#define BN 128
#define BK 64
#define SCALE_F 0.8944271909999159f
// worst-case sum of m-tiles over 9 experts: 32 (shared) + 71 (routed) = 103
#define PMAX 103

typedef __attribute__((ext_vector_type(8))) short short8;
typedef __attribute__((ext_vector_type(4))) float floatx4;

// async global->LDS, 16B/lane; LDS dest = wave-uniform base + lane*16 (m97/m104)
#define GLD16(gp, lp) __builtin_amdgcn_global_load_lds( \
    (const __attribute__((address_space(1))) void*)(gp), \
    (__attribute__((address_space(3))) void*)(lp), 16, 0, 0)

__device__ __forceinline__ ushort f2bf(float f){
    __hip_bfloat16 h = __float2bfloat16(f);
    return *reinterpret_cast<ushort*>(&h);
}

// 0.5x(1+tanh(u)) == x * sigmoid(2u), exp-form: ~6 VALU vs ~50 for tanhf
__device__ __forceinline__ float gelu_tanh(float v){
    float u2 = -1.5957691216057308f * (v + 0.044715f * v * v * v);
    return v / (1.0f + __expf(u2));
}

// one fused bf16-convert over all 5 fp32 arrays.
// 8 floats per thread: 2x float4 loads -> 1x 16B short8 store (full-width stores).
#define CV8_N0 524288u             // x        : 4096*1024/8
#define CV8_N1 4718592u            // + W1     : 8*4096*1024/8
#define CV8_N2 8912896u            // + W2
#define CV8_N3 9437184u            // + Ws1
#define CV8_N4 9961472u            // + Ws2  (total; grid = total/256 = 38912)
__global__ __launch_bounds__(256) void cvt_all(
    const float* __restrict__ x,  const float* __restrict__ W1,
    const float* __restrict__ W2, const float* __restrict__ Ws1,
    const float* __restrict__ Ws2,
    ushort* __restrict__ xb,  ushort* __restrict__ w1b, ushort* __restrict__ w2b,
    ushort* __restrict__ ws1b, ushort* __restrict__ ws2b)
{
    unsigned i = blockIdx.x * 256u + threadIdx.x;
    const float* s; ushort* d; unsigned off;
    if      (i < CV8_N0){ s = x;   d = xb;   off = i; }
    else if (i < CV8_N1){ s = W1;  d = w1b;  off = i - CV8_N0; }
    else if (i < CV8_N2){ s = W2;  d = w2b;  off = i - CV8_N1; }
    else if (i < CV8_N3){ s = Ws1; d = ws1b; off = i - CV8_N2; }
    else                { s = Ws2; d = ws2b; off = i - CV8_N3; }
    const float4* s4 = reinterpret_cast<const float4*>(s) + 2 * (size_t)off;
    float4 a = s4[0];
    float4 b = s4[1];
    short8 o;
    o[0] = (short)f2bf(a.x); o[1] = (short)f2bf(a.y);
    o[2] = (short)f2bf(a.z); o[3] = (short)f2bf(a.w);
    o[4] = (short)f2bf(b.x); o[5] = (short)f2bf(b.y);
    o[6] = (short)f2bf(b.z); o[7] = (short)f2bf(b.w);
    reinterpret_cast<short8*>(d)[off] = o;
}

// one wave per token: fp32 logits -> softmax -> top2
__global__ __launch_bounds__(256) void router_kernel(
    const float* __restrict__ x, const float* __restrict__ wr,
    int* __restrict__ te, float* __restrict__ tg, int* __restrict__ tokarr)
{
    const int token = blockIdx.x * 4 + (threadIdx.x >> 6);
    const int lane  = threadIdx.x & 63;
    const float* xp = x + (size_t)token * DM;
    float s[8];
    #pragma unroll
    for (int e = 0; e < 8; e++) s[e] = 0.f;
    for (int d = lane; d < DM; d += 64){
        float xv = xp[d];
        #pragma unroll
        for (int e = 0; e < 8; e++) s[e] += xv * wr[e * DM + d];
    }
    #pragma unroll
    for (int e = 0; e < 8; e++){
        float v = s[e];
        #pragma unroll
        for (int off = 32; off > 0; off >>= 1) v += __shfl_down(v, off);
        s[e] = v;
    }
    if (lane == 0){
        float m = s[0];
        #pragma unroll
        for (int e = 1; e < 8; e++) m = fmaxf(m, s[e]);
        float p[8]; float sum = 0.f;
        #pragma unroll
        for (int e = 0; e < 8; e++){ p[e] = __expf(s[e] - m); sum += p[e]; }
        float inv = 1.f / sum;
        #pragma unroll
        for (int e = 0; e < 8; e++) p[e] *= inv;
        int i1 = 0; float p1 = p[0];
        #pragma unroll
        for (int e = 1; e < 8; e++) if (p[e] > p1){ p1 = p[e]; i1 = e; }
        int i2 = -1; float p2 = -1.f;
        #pragma unroll
        for (int e = 0; e < 8; e++) if (e != i1 && p[e] > p2){ p2 = p[e]; i2 = e; }
        te[token*2+0] = i1; te[token*2+1] = i2;
        tg[token*2+0] = p1; tg[token*2+1] = p2;
        tokarr[token] = token;      // shared-expert rows = identity
    }
}

// single 256-thread block: counts -> prefix/meta -> scatter routed rows.
// meta layout: [0..8]=counts, [16..24]=rowbase, [32..40]=mtiles
__global__ __launch_bounds__(256) void plan_kernel(
    const int* __restrict__ te, int* __restrict__ tokarr,
    int* __restrict__ rowof, int* __restrict__ meta)
{
    __shared__ int lc[9], lcur[9];
    const int t = threadIdx.x;
    if (t < 9) lc[t] = 0;
    __syncthreads();
    for (int j = t; j < NTOK*2; j += 256) atomicAdd(&lc[te[j]], 1);
    __syncthreads();
    if (t == 0){
        int off = NTOK;
        for (int e = 0; e < 8; e++){
            lcur[e]    = off;
            meta[e]    = lc[e];
            meta[16+e] = off;
            meta[32+e] = (lc[e] + BM - 1) / BM;
            off += lc[e];
        }
        meta[8]    = NTOK;      // shared expert
        meta[16+8] = 0;
        meta[32+8] = NTOK / BM;
    }
    __syncthreads();
    for (int j = t; j < NTOK*2; j += 256){
        int e = te[j];
        int p = atomicAdd(&lcur[e], 1);
        tokarr[p] = j >> 1;
        rowof[j]  = p;
    }
}

// MODE 0: H[row] = gelu(Xg @ W1_e^T + b1)   (N=4096=32 nt, K=1024) -> bf16 H
// MODE 1: Y[row] = H @ W2_e^T + b2          (N=1024= 8 nt, K=4096) -> fp32 Y
// XCD-aware schedule (unchanged). K-loop upgraded to the T3 minimum 2-phase
// pipeline: double-buffered LDS, prefetch issued BEFORE compute, raw s_barrier
// + asm vmcnt(0) placed AFTER compute so HBM/L2 latency hides under the MFMAs.
template<int MODE>
__global__ __launch_bounds__(256) void gemm_kernel(
    const ushort* __restrict__ Abase,
    const ushort* __restrict__ Wb, const ushort* __restrict__ Wsb,
    const float* __restrict__ brout, const float* __restrict__ bsh,
    const int* __restrict__ meta, const int* __restrict__ tokarr,
    ushort* __restrict__ Hout, float* __restrict__ Yout)
{
    const int xcd = blockIdx.x & 7;
    const int q   = blockIdx.x >> 3;
    const int NTG = (MODE == 0) ? 4 : 1;     // nt-columns per expert per XCD

    int e = -1, r = 0, a0 = 0;
    #pragma unroll
    for (int ee = 0; ee < 9; ee++){
        int w = NTG * meta[32 + ee];
        if (e < 0 && q < a0 + w){ e = ee; r = q - a0; }
        a0 += w;
    }
    if (e < 0) return;
    const int mt_e = meta[32 + e];
    int ntg, mti;
    if (MODE == 0){ ntg = r / mt_e; mti = r - ntg * mt_e; }
    else          { ntg = 0;        mti = r; }
    const int nt   = (MODE == 0) ? (xcd + 8 * ntg) : xcd;
    const int cnt  = meta[e];
    const int base = meta[16 + e];

    const int K = (MODE == 0) ? DM : DF;
    const int N = (MODE == 0) ? DF : DM;
    const ushort* Bp  = (e < 8) ? (Wb + (size_t)e * DF * DM) : Wsb;
    const float* bias = (e < 8) ? (brout + e * N) : bsh;

    __shared__ ushort As[2][BM * BK];   // unpadded: required by global_load_lds
    __shared__ ushort Bs[2][BN * BK];

    const int t    = threadIdx.x;
    const int lane = t & 63;
    const int wv   = t >> 6;
    const int wm   = (wv >> 1) * 64;
    const int wn   = (wv & 1) * 64;
    const int lrow = lane & 15;
    const int quad = lane >> 4;
    // column swizzle (16B units): phys_seg = log_seg ^ (row&7)
    const int swz8 = ((lane & 7) ^ (lane >> 3)) * 8;

    const ushort* Ap[4];
    const ushort* Bpp[4];
    ushort* Alds0[4]; ushort* Alds1[4];
    ushort* Blds0[4]; ushort* Blds1[4];
    #pragma unroll
    for (int i = 0; i < 4; i++){
        int rin = wv * 32 + i * 8 + (lane >> 3);
        int pos = mti * BM + rin;
        int clp = (pos < cnt) ? pos : (cnt - 1);
        if (MODE == 0) Ap[i] = Abase + (size_t)tokarr[base + clp] * DM + swz8;
        else           Ap[i] = Abase + (size_t)(base + clp) * DF + swz8;
        Bpp[i]   = Bp + (size_t)(nt * BN + rin) * K + swz8;
        Alds0[i] = &As[0][(wv * 32 + i * 8) * BK];
        Alds1[i] = &As[1][(wv * 32 + i * 8) * BK];
        Blds0[i] = &Bs[0][(wv * 32 + i * 8) * BK];
        Blds1[i] = &Bs[1][(wv * 32 + i * 8) * BK];
    }

    floatx4 acc[4][4];
    #pragma unroll
    for (int mi = 0; mi < 4; mi++)
        #pragma unroll
        for (int ni = 0; ni < 4; ni++)
            acc[mi][ni] = (floatx4){0.f, 0.f, 0.f, 0.f};

    auto compute = [&](const ushort* Asb, const ushort* Bsb){
        #pragma unroll
        for (int kk = 0; kk < BK; kk += 32){
            short8 af[4], bfr[4];
            #pragma unroll
            for (int mi = 0; mi < 4; mi++){
                int row  = wm + mi * 16 + lrow;
                int phys = ((kk >> 3) + quad) ^ (row & 7);
                af[mi] = *reinterpret_cast<const short8*>(&Asb[row * BK + phys * 8]);
            }
            #pragma unroll
            for (int ni = 0; ni < 4; ni++){
                int row  = wn + ni * 16 + lrow;
                int phys = ((kk >> 3) + quad) ^ (row & 7);
                bfr[ni] = *reinterpret_cast<const short8*>(&Bsb[row * BK + phys * 8]);
            }
            #pragma unroll
            for (int mi = 0; mi < 4; mi++)
                #pragma unroll
                for (int ni = 0; ni < 4; ni++)
                    acc[mi][ni] = __builtin_amdgcn_mfma_f32_16x16x32_bf16(af[mi], bfr[ni], acc[mi][ni], 0, 0, 0);
        }
    };

    // prologue: stage tile 0 -> buf0, drain, sync
    #pragma unroll
    for (int i = 0; i < 4; i++){
        GLD16(Ap[i], Alds0[i]);
        GLD16(Bpp[i], Blds0[i]);
    }
    asm volatile("s_waitcnt vmcnt(0)" ::: "memory");
    __builtin_amdgcn_s_barrier();

    // main loop, 2 K-tiles per iteration (K is a multiple of 2*BK for both modes)
    #pragma unroll 1
    for (int k0 = 0; k0 < K; k0 += 2 * BK){
        // phase A: prefetch tile(k0+BK) -> buf1 ; compute buf0
        #pragma unroll
        for (int i = 0; i < 4; i++){
            GLD16(Ap[i]  + k0 + BK, Alds1[i]);
            GLD16(Bpp[i] + k0 + BK, Blds1[i]);
        }
        compute(As[0], Bs[0]);
        asm volatile("s_waitcnt vmcnt(0)" ::: "memory");
        __builtin_amdgcn_s_barrier();

        // phase B: prefetch tile(k0+2BK) -> buf0 (if any) ; compute buf1
        if (k0 + 2 * BK < K){
            #pragma unroll
            for (int i = 0; i < 4; i++){
                GLD16(Ap[i]  + k0 + 2 * BK, Alds0[i]);
                GLD16(Bpp[i] + k0 + 2 * BK, Blds0[i]);
            }
        }
        compute(As[1], Bs[1]);
        asm volatile("s_waitcnt vmcnt(0)" ::: "memory");
        __builtin_amdgcn_s_barrier();
    }

    // epilogue; C/D: col = lane&15, row = quad*4 + reg  [m89]
    float bv[4];
    #pragma unroll
    for (int ni = 0; ni < 4; ni++) bv[ni] = bias[nt * BN + wn + ni*16 + lrow];

    #pragma unroll
    for (int mi = 0; mi < 4; mi++){
        #pragma unroll
        for (int rg = 0; rg < 4; rg++){
            int s   = wm + mi*16 + quad*4 + rg;
            int pos = mti * BM + s;
            if (pos >= cnt) continue;
            int rr = base + pos;
            if (MODE == 0){
                ushort* hp = Hout + (size_t)rr * DF + nt * BN;
                #pragma unroll
                for (int ni = 0; ni < 4; ni++){
                    float v = acc[mi][ni][rg] + bv[ni];
                    hp[wn + ni*16 + lrow] = f2bf(gelu_tanh(v));
                }
            } else {
                float* yp = Yout + (size_t)rr * DM + nt * BN;
                #pragma unroll
                for (int ni = 0; ni < 4; ni++)
                    yp[wn + ni*16 + lrow] = acc[mi][ni][rg] + bv[ni];
            }
        }
    }
}

// out[t] = SCALE * (Y[t] + g1*Y[r1] + g2*Y[r2])
__global__ __launch_bounds__(256) void combine_kernel(
    const float* __restrict__ Y, const int* __restrict__ rowof,
    const float* __restrict__ tg, float* __restrict__ out)
{
    const int token = blockIdx.x;
    const int d4    = threadIdx.x;
    const float4* Y4 = reinterpret_cast<const float4*>(Y);
    int r1 = rowof[token*2+0], r2 = rowof[token*2+1];
    float g1 = tg[token*2+0],  g2 = tg[token*2+1];
    float4 a = Y4[(size_t)token * 256 + d4];
    float4 b = Y4[(size_t)r1 * 256 + d4];
    float4 c = Y4[(size_t)r2 * 256 + d4];
    float4 o;
    o.x = SCALE_F * (a.x + g1*b.x + g2*c.x);
    o.y = SCALE_F * (a.y + g1*b.y + g2*c.y);
    o.z = SCALE_F * (a.z + g1*b.z + g2*c.z);
    o.w = SCALE_F * (a.w + g1*b.w + g2*c.w);
    reinterpret_cast<float4*>(out)[(size_t)token * 256 + d4] = o;
}

extern "C" void kernel_launch(void* const* d_in, const int* in_sizes, int n_in,
                              void* d_out, int out_size, void* d_ws, size_t ws_size,
                              hipStream_t stream) {
    const float* x   = (const float*)d_in[0];
    const float* wr  = (const float*)d_in[1];
    const float* W1  = (const float*)d_in[2];
    const float* b1  = (const float*)d_in[3];
    const float* W2  = (const float*)d_in[4];
    const float* b2  = (const float*)d_in[5];
    const float* Ws1 = (const float*)d_in[6];
    const float* bs1 = (const float*)d_in[7];
    const float* Ws2 = (const float*)d_in[8];
    const float* bs2 = (const float*)d_in[9];
    float* out = (float*)d_out;

    char* ws = (char*)d_ws;
    size_t off = 0;
    auto wsalloc = [&](size_t bytes) -> char* {
        char* p = ws + off;
        off += (bytes + 255) & ~(size_t)255;
        return p;
    };
    ushort* xb   = (ushort*)wsalloc((size_t)NTOK * DM * 2);
    ushort* w1b  = (ushort*)wsalloc((size_t)8 * DF * DM * 2);
    ushort* w2b  = (ushort*)wsalloc((size_t)8 * DM * DF * 2);
    ushort* ws1b = (ushort*)wsalloc((size_t)DF * DM * 2);
    ushort* ws2b = (ushort*)wsalloc((size_t)DM * DF * 2);
    ushort* H    = (ushort*)wsalloc((size_t)ROWS_TOTAL * DF * 2);
    int*    tokarr = (int*)wsalloc(ROWS_TOTAL * 4);
    int*    rowof  = (int*)wsalloc(NTOK * 2 * 4);
    int*    te     = (int*)wsalloc(NTOK * 2 * 4);
    float*  tg     = (float*)wsalloc(NTOK * 2 * 4);
    int*    meta   = (int*)wsalloc(64 * 4);
    // Y (50.3MB fp32) aliases w1b (67MB): w1b dead after gemm1, Y born in gemm2
    float*  Y = (float*)w1b;

    cvt_all<<<CV8_N4/256, 256, 0, stream>>>(x, W1, W2, Ws1, Ws2,
                                            xb, w1b, w2b, ws1b, ws2b);
    router_kernel<<<NTOK/4, 256, 0, stream>>>(x, wr, te, tg, tokarr);
    plan_kernel<<<1, 256, 0, stream>>>(te, tokarr, rowof, meta);

    // grid = 8 XCD lanes x worst-case per-XCD queue length
    gemm_kernel<0><<<8 * 4 * PMAX, 256, 0, stream>>>(xb, w1b, ws1b, b1, bs1,
        meta, tokarr, H, Y);
    gemm_kernel<1><<<8 * PMAX, 256, 0, stream>>>(H, w2b, ws2b, b2, bs2,
        meta, tokarr, H, Y);

    combine_kernel<<<NTOK, 256, 0, stream>>>(Y, rowof, tg, out);
}

// Round 4
// 731.238 us; speedup vs baseline: 1.1173x; 1.1173x over previous
//
#include <hip/hip_runtime.h>
#include <hip/hip_bf16.h>

#define NTOK 4096
#define DM   1024
#define DF   4096
#define ROWS_TOTAL 12288   // 4096 shared + 8192 routed (top-2)
#define BM 128
#define BN 128
#define BK 64
#define SCALE_F 0.8944271909999159f
// worst-case sum of m-tiles over 9 experts: 32 (shared) + 71 (routed) = 103
#define PMAX 103

typedef __attribute__((ext_vector_type(8))) short short8;
typedef __attribute__((ext_vector_type(4))) float floatx4;

// async global->LDS, 16B/lane; LDS dest = wave-uniform base + lane*16 (m97/m104)
#define GLD16(gp, lp) __builtin_amdgcn_global_load_lds( \
    (const __attribute__((address_space(1))) void*)(gp), \
    (__attribute__((address_space(3))) void*)(lp), 16, 0, 0)

__device__ __forceinline__ ushort f2bf(float f){
    __hip_bfloat16 h = __float2bfloat16(f);
    return *reinterpret_cast<ushort*>(&h);
}

// 0.5x(1+tanh(u)) == x * sigmoid(2u), exp-form: ~6 VALU vs ~50 for tanhf
__device__ __forceinline__ float gelu_tanh(float v){
    float u2 = -1.5957691216057308f * (v + 0.044715f * v * v * v);
    return v / (1.0f + __expf(u2));
}

// one fused bf16-convert over all 5 fp32 arrays.
// 8 floats per thread: 2x float4 loads -> 1x 16B short8 store (full-width stores).
#define CV8_N0 524288u             // x        : 4096*1024/8
#define CV8_N1 4718592u            // + W1     : 8*4096*1024/8
#define CV8_N2 8912896u            // + W2
#define CV8_N3 9437184u            // + Ws1
#define CV8_N4 9961472u            // + Ws2  (total; grid = total/256 = 38912)
__global__ __launch_bounds__(256) void cvt_all(
    const float* __restrict__ x,  const float* __restrict__ W1,
    const float* __restrict__ W2, const float* __restrict__ Ws1,
    const float* __restrict__ Ws2,
    ushort* __restrict__ xb,  ushort* __restrict__ w1b, ushort* __restrict__ w2b,
    ushort* __restrict__ ws1b, ushort* __restrict__ ws2b)
{
    unsigned i = blockIdx.x * 256u + threadIdx.x;
    const float* s; ushort* d; unsigned off;
    if      (i < CV8_N0){ s = x;   d = xb;   off = i; }
    else if (i < CV8_N1){ s = W1;  d = w1b;  off = i - CV8_N0; }
    else if (i < CV8_N2){ s = W2;  d = w2b;  off = i - CV8_N1; }
    else if (i < CV8_N3){ s = Ws1; d = ws1b; off = i - CV8_N2; }
    else                { s = Ws2; d = ws2b; off = i - CV8_N3; }
    const float4* s4 = reinterpret_cast<const float4*>(s) + 2 * (size_t)off;
    float4 a = s4[0];
    float4 b = s4[1];
    short8 o;
    o[0] = (short)f2bf(a.x); o[1] = (short)f2bf(a.y);
    o[2] = (short)f2bf(a.z); o[3] = (short)f2bf(a.w);
    o[4] = (short)f2bf(b.x); o[5] = (short)f2bf(b.y);
    o[6] = (short)f2bf(b.z); o[7] = (short)f2bf(b.w);
    reinterpret_cast<short8*>(d)[off] = o;
}

// one wave per token: fp32 logits -> softmax -> top2
__global__ __launch_bounds__(256) void router_kernel(
    const float* __restrict__ x, const float* __restrict__ wr,
    int* __restrict__ te, float* __restrict__ tg, int* __restrict__ tokarr)
{
    const int token = blockIdx.x * 4 + (threadIdx.x >> 6);
    const int lane  = threadIdx.x & 63;
    const float* xp = x + (size_t)token * DM;
    float s[8];
    #pragma unroll
    for (int e = 0; e < 8; e++) s[e] = 0.f;
    for (int d = lane; d < DM; d += 64){
        float xv = xp[d];
        #pragma unroll
        for (int e = 0; e < 8; e++) s[e] += xv * wr[e * DM + d];
    }
    #pragma unroll
    for (int e = 0; e < 8; e++){
        float v = s[e];
        #pragma unroll
        for (int off = 32; off > 0; off >>= 1) v += __shfl_down(v, off);
        s[e] = v;
    }
    if (lane == 0){
        float m = s[0];
        #pragma unroll
        for (int e = 1; e < 8; e++) m = fmaxf(m, s[e]);
        float p[8]; float sum = 0.f;
        #pragma unroll
        for (int e = 0; e < 8; e++){ p[e] = __expf(s[e] - m); sum += p[e]; }
        float inv = 1.f / sum;
        #pragma unroll
        for (int e = 0; e < 8; e++) p[e] *= inv;
        int i1 = 0; float p1 = p[0];
        #pragma unroll
        for (int e = 1; e < 8; e++) if (p[e] > p1){ p1 = p[e]; i1 = e; }
        int i2 = -1; float p2 = -1.f;
        #pragma unroll
        for (int e = 0; e < 8; e++) if (e != i1 && p[e] > p2){ p2 = p[e]; i2 = e; }
        te[token*2+0] = i1; te[token*2+1] = i2;
        tg[token*2+0] = p1; tg[token*2+1] = p2;
        tokarr[token] = token;      // shared-expert rows = identity
    }
}

// single 256-thread block: counts -> prefix/meta -> scatter routed rows.
// meta layout: [0..8]=counts, [16..24]=rowbase, [32..40]=mtiles
__global__ __launch_bounds__(256) void plan_kernel(
    const int* __restrict__ te, int* __restrict__ tokarr,
    int* __restrict__ rowof, int* __restrict__ meta)
{
    __shared__ int lc[9], lcur[9];
    const int t = threadIdx.x;
    if (t < 9) lc[t] = 0;
    __syncthreads();
    for (int j = t; j < NTOK*2; j += 256) atomicAdd(&lc[te[j]], 1);
    __syncthreads();
    if (t == 0){
        int off = NTOK;
        for (int e = 0; e < 8; e++){
            lcur[e]    = off;
            meta[e]    = lc[e];
            meta[16+e] = off;
            meta[32+e] = (lc[e] + BM - 1) / BM;
            off += lc[e];
        }
        meta[8]    = NTOK;      // shared expert
        meta[16+8] = 0;
        meta[32+8] = NTOK / BM;
    }
    __syncthreads();
    for (int j = t; j < NTOK*2; j += 256){
        int e = te[j];
        int p = atomicAdd(&lcur[e], 1);
        tokarr[p] = j >> 1;
        rowof[j]  = p;
    }
}

// MODE 0: H[row] = gelu(Xg @ W1_e^T + b1)   (N=4096=32 nt, K=1024) -> bf16 H
// MODE 1: Y[row] = H @ W2_e^T + b2          (N=1024= 8 nt, K=4096) -> fp32 Y
// XCD-aware schedule (unchanged). 2-phase double-buffered pipeline, reordered
// so ds_reads precede GLD issues (no conservative alias-wait possible: vmcnt
// is drained at every ds_read point). Loads overlap the 32-MFMA cluster.
// ONE barrier per K-step, via plain __syncthreads() (known-good primitive;
// identical semantics to manual vmcnt(0)+s_barrier). sched_barrier(0) is a
// compile-time fence only — emits no instruction.
template<int MODE>
__global__ __launch_bounds__(256) void gemm_kernel(
    const ushort* __restrict__ Abase,
    const ushort* __restrict__ Wb, const ushort* __restrict__ Wsb,
    const float* __restrict__ brout, const float* __restrict__ bsh,
    const int* __restrict__ meta, const int* __restrict__ tokarr,
    ushort* __restrict__ Hout, float* __restrict__ Yout)
{
    const int xcd = blockIdx.x & 7;
    const int q   = blockIdx.x >> 3;
    const int NTG = (MODE == 0) ? 4 : 1;     // nt-columns per expert per XCD

    int e = -1, r = 0, a0 = 0;
    #pragma unroll
    for (int ee = 0; ee < 9; ee++){
        int w = NTG * meta[32 + ee];
        if (e < 0 && q < a0 + w){ e = ee; r = q - a0; }
        a0 += w;
    }
    if (e < 0) return;
    const int mt_e = meta[32 + e];
    int ntg, mti;
    if (MODE == 0){ ntg = r / mt_e; mti = r - ntg * mt_e; }
    else          { ntg = 0;        mti = r; }
    const int nt   = (MODE == 0) ? (xcd + 8 * ntg) : xcd;
    const int cnt  = meta[e];
    const int base = meta[16 + e];

    const int K = (MODE == 0) ? DM : DF;
    const int N = (MODE == 0) ? DF : DM;
    const ushort* Bp  = (e < 8) ? (Wb + (size_t)e * DF * DM) : Wsb;
    const float* bias = (e < 8) ? (brout + e * N) : bsh;

    __shared__ ushort As[2][BM * BK];   // unpadded: required by global_load_lds
    __shared__ ushort Bs[2][BN * BK];

    const int t    = threadIdx.x;
    const int lane = t & 63;
    const int wv   = t >> 6;
    const int wm   = (wv >> 1) * 64;
    const int wn   = (wv & 1) * 64;
    const int lrow = lane & 15;
    const int quad = lane >> 4;
    // column swizzle (16B units): phys_seg = log_seg ^ (row&7)
    const int swz8 = ((lane & 7) ^ (lane >> 3)) * 8;

    const ushort* Ap[4];
    const ushort* Bpp[4];
    ushort* Alds0[4]; ushort* Alds1[4];
    ushort* Blds0[4]; ushort* Blds1[4];
    #pragma unroll
    for (int i = 0; i < 4; i++){
        int rin = wv * 32 + i * 8 + (lane >> 3);
        int pos = mti * BM + rin;
        int clp = (pos < cnt) ? pos : (cnt - 1);
        if (MODE == 0) Ap[i] = Abase + (size_t)tokarr[base + clp] * DM + swz8;
        else           Ap[i] = Abase + (size_t)(base + clp) * DF + swz8;
        Bpp[i]   = Bp + (size_t)(nt * BN + rin) * K + swz8;
        Alds0[i] = &As[0][(wv * 32 + i * 8) * BK];
        Alds1[i] = &As[1][(wv * 32 + i * 8) * BK];
        Blds0[i] = &Bs[0][(wv * 32 + i * 8) * BK];
        Blds1[i] = &Bs[1][(wv * 32 + i * 8) * BK];
    }

    floatx4 acc[4][4];
    #pragma unroll
    for (int mi = 0; mi < 4; mi++)
        #pragma unroll
        for (int ni = 0; ni < 4; ni++)
            acc[mi][ni] = (floatx4){0.f, 0.f, 0.f, 0.f};

    // one phase = consume one LDS buffer + prefetch into the other.
    // Order: ds_read ALL frags -> fence -> GLD issue -> fence -> MFMA -> syncthreads.
    auto phase = [&](const ushort* Asb, const ushort* Bsb,
                     ushort* const* Aldsn, ushort* const* Bldsn,
                     int knext, bool pf){
        short8 af0[4], bf0[4], af1[4], bf1[4];
        #pragma unroll
        for (int mi = 0; mi < 4; mi++){
            int row = wm + mi * 16 + lrow;
            int p0  = (0 + quad) ^ (row & 7);
            int p1  = (4 + quad) ^ (row & 7);
            af0[mi] = *reinterpret_cast<const short8*>(&Asb[row * BK + p0 * 8]);
            af1[mi] = *reinterpret_cast<const short8*>(&Asb[row * BK + p1 * 8]);
        }
        #pragma unroll
        for (int ni = 0; ni < 4; ni++){
            int row = wn + ni * 16 + lrow;
            int p0  = (0 + quad) ^ (row & 7);
            int p1  = (4 + quad) ^ (row & 7);
            bf0[ni] = *reinterpret_cast<const short8*>(&Bsb[row * BK + p0 * 8]);
            bf1[ni] = *reinterpret_cast<const short8*>(&Bsb[row * BK + p1 * 8]);
        }
        __builtin_amdgcn_sched_barrier(0);   // keep GLD issues after ds_reads
        if (pf){
            #pragma unroll
            for (int i = 0; i < 4; i++){
                GLD16(Ap[i]  + knext, Aldsn[i]);
                GLD16(Bpp[i] + knext, Bldsn[i]);
            }
        }
        __builtin_amdgcn_sched_barrier(0);   // keep MFMAs after GLD issues
        #pragma unroll
        for (int mi = 0; mi < 4; mi++)
            #pragma unroll
            for (int ni = 0; ni < 4; ni++)
                acc[mi][ni] = __builtin_amdgcn_mfma_f32_16x16x32_bf16(af0[mi], bf0[ni], acc[mi][ni], 0, 0, 0);
        #pragma unroll
        for (int mi = 0; mi < 4; mi++)
            #pragma unroll
            for (int ni = 0; ni < 4; ni++)
                acc[mi][ni] = __builtin_amdgcn_mfma_f32_16x16x32_bf16(af1[mi], bf1[ni], acc[mi][ni], 0, 0, 0);
        __syncthreads();   // drains vmcnt (GLD16s) + barrier — known-good primitive
    };

    // prologue: stage tile 0 -> buf0, drain, sync
    #pragma unroll
    for (int i = 0; i < 4; i++){
        GLD16(Ap[i], Alds0[i]);
        GLD16(Bpp[i], Blds0[i]);
    }
    __syncthreads();

    // main loop, 2 K-tiles per iteration (K is a multiple of 2*BK for both modes)
    #pragma unroll 1
    for (int k0 = 0; k0 < K; k0 += 2 * BK){
        phase(As[0], Bs[0], Alds1, Blds1, k0 + BK,     true);
        phase(As[1], Bs[1], Alds0, Blds0, k0 + 2 * BK, k0 + 2 * BK < K);
    }

    // epilogue; C/D: col = lane&15, row = quad*4 + reg  [m89]
    float bv[4];
    #pragma unroll
    for (int ni = 0; ni < 4; ni++) bv[ni] = bias[nt * BN + wn + ni*16 + lrow];

    #pragma unroll
    for (int mi = 0; mi < 4; mi++){
        #pragma unroll
        for (int rg = 0; rg < 4; rg++){
            int s   = wm + mi*16 + quad*4 + rg;
            int pos = mti * BM + s;
            if (pos >= cnt) continue;
            int rr = base + pos;
            if (MODE == 0){
                ushort* hp = Hout + (size_t)rr * DF + nt * BN;
                #pragma unroll
                for (int ni = 0; ni < 4; ni++){
                    float v = acc[mi][ni][rg] + bv[ni];
                    hp[wn + ni*16 + lrow] = f2bf(gelu_tanh(v));
                }
            } else {
                float* yp = Yout + (size_t)rr * DM + nt * BN;
                #pragma unroll
                for (int ni = 0; ni < 4; ni++)
                    yp[wn + ni*16 + lrow] = acc[mi][ni][rg] + bv[ni];
            }
        }
    }
}

// out[t] = SCALE * (Y[t] + g1*Y[r1] + g2*Y[r2])
__global__ __launch_bounds__(256) void combine_kernel(
    const float* __restrict__ Y, const int* __restrict__ rowof,
    const float* __restrict__ tg, float* __restrict__ out)
{
    const int token = blockIdx.x;
    const int d4    = threadIdx.x;
    const float4* Y4 = reinterpret_cast<const float4*>(Y);
    int r1 = rowof[token*2+0], r2 = rowof[token*2+1];
    float g1 = tg[token*2+0],  g2 = tg[token*2+1];
    float4 a = Y4[(size_t)token * 256 + d4];
    float4 b = Y4[(size_t)r1 * 256 + d4];
    float4 c = Y4[(size_t)r2 * 256 + d4];
    float4 o;
    o.x = SCALE_F * (a.x + g1*b.x + g2*c.x);
    o.y = SCALE_F * (a.y + g1*b.y + g2*c.y);
    o.z = SCALE_F * (a.z + g1*b.z + g2*c.z);
    o.w = SCALE_F * (a.w + g1*b.w + g2*c.w);
    reinterpret_cast<float4*>(out)[(size_t)token * 256 + d4] = o;
}

extern "C" void kernel_launch(void* const* d_in, const int* in_sizes, int n_in,
                              void* d_out, int out_size, void* d_ws, size_t ws_size,
                              hipStream_t stream) {
    const float* x   = (const float*)d_in[0];
    const float* wr  = (const float*)d_in[1];
    const float* W1  = (const float*)d_in[2];
    const float* b1  = (const float*)d_in[3];
    const float* W2  = (const float*)d_in[4];
    const float* b2  = (const float*)d_in[5];
    const float* Ws1 = (const float*)d_in[6];
    const float* bs1 = (const float*)d_in[7];
    const float* Ws2 = (const float*)d_in[8];
    const float* bs2 = (const float*)d_in[9];
    float* out = (float*)d_out;

    char* ws = (char*)d_ws;
    size_t off = 0;
    auto wsalloc = [&](size_t bytes) -> char* {
        char* p = ws + off;
        off += (bytes + 255) & ~(size_t)255;
        return p;
    };
    ushort* xb   = (ushort*)wsalloc((size_t)NTOK * DM * 2);
    ushort* w1b  = (ushort*)wsalloc((size_t)8 * DF * DM * 2);
    ushort* w2b  = (ushort*)wsalloc((size_t)8 * DM * DF * 2);
    ushort* ws1b = (ushort*)wsalloc((size_t)DF * DM * 2);
    ushort* ws2b = (ushort*)wsalloc((size_t)DM * DF * 2);
    ushort* H    = (ushort*)wsalloc((size_t)ROWS_TOTAL * DF * 2);
    int*    tokarr = (int*)wsalloc(ROWS_TOTAL * 4);
    int*    rowof  = (int*)wsalloc(NTOK * 2 * 4);
    int*    te     = (int*)wsalloc(NTOK * 2 * 4);
    float*  tg     = (float*)wsalloc(NTOK * 2 * 4);
    int*    meta   = (int*)wsalloc(64 * 4);
    // Y (50.3MB fp32) aliases w1b (67MB): w1b dead after gemm1, Y born in gemm2
    float*  Y = (float*)w1b;

    cvt_all<<<CV8_N4/256, 256, 0, stream>>>(x, W1, W2, Ws1, Ws2,
                                            xb, w1b, w2b, ws1b, ws2b);
    router_kernel<<<NTOK/4, 256, 0, stream>>>(x, wr, te, tg, tokarr);
    plan_kernel<<<1, 256, 0, stream>>>(te, tokarr, rowof, meta);

    // grid = 8 XCD lanes x worst-case per-XCD queue length
    gemm_kernel<0><<<8 * 4 * PMAX, 256, 0, stream>>>(xb, w1b, ws1b, b1, bs1,
        meta, tokarr, H, Y);
    gemm_kernel<1><<<8 * PMAX, 256, 0, stream>>>(H, w2b, ws2b, b2, bs2,
        meta, tokarr, H, Y);

    combine_kernel<<<NTOK, 256, 0, stream>>>(Y, rowof, tg, out);
}

// Round 5
// 730.881 us; speedup vs baseline: 1.1179x; 1.0005x over previous
//
#include <hip/hip_runtime.h>
#include <hip/hip_bf16.h>

#define NTOK 4096
#define DM   1024
#define DF   4096
#define ROWS_TOTAL 12288   // 4096 shared + 8192 routed (top-2)
#define BM 128
#define BN 128
#define SCALE_F 0.8944271909999159f
// worst-case sum of m-tiles over 9 experts: 32 (shared) + 71 (routed) = 103
#define PMAX 103

typedef __attribute__((ext_vector_type(8))) short short8;
typedef __attribute__((ext_vector_type(4))) float floatx4;

// async global->LDS, 16B/lane; LDS dest = wave-uniform base + lane*16 (m97/m104)
#define GLD16(gp, lp) __builtin_amdgcn_global_load_lds( \
    (const __attribute__((address_space(1))) void*)(gp), \
    (__attribute__((address_space(3))) void*)(lp), 16, 0, 0)

__device__ __forceinline__ ushort f2bf(float f){
    __hip_bfloat16 h = __float2bfloat16(f);
    return *reinterpret_cast<ushort*>(&h);
}

// 0.5x(1+tanh(u)) == x * sigmoid(2u), exp-form: ~6 VALU vs ~50 for tanhf
__device__ __forceinline__ float gelu_tanh(float v){
    float u2 = -1.5957691216057308f * (v + 0.044715f * v * v * v);
    return v / (1.0f + __expf(u2));
}

// one fused bf16-convert over all 5 fp32 arrays.
// 8 floats per thread: 2x float4 loads -> 1x 16B short8 store (full-width stores).
#define CV8_N0 524288u             // x        : 4096*1024/8
#define CV8_N1 4718592u            // + W1     : 8*4096*1024/8
#define CV8_N2 8912896u            // + W2
#define CV8_N3 9437184u            // + Ws1
#define CV8_N4 9961472u            // + Ws2  (total; grid = total/256 = 38912)
__global__ __launch_bounds__(256) void cvt_all(
    const float* __restrict__ x,  const float* __restrict__ W1,
    const float* __restrict__ W2, const float* __restrict__ Ws1,
    const float* __restrict__ Ws2,
    ushort* __restrict__ xb,  ushort* __restrict__ w1b, ushort* __restrict__ w2b,
    ushort* __restrict__ ws1b, ushort* __restrict__ ws2b)
{
    unsigned i = blockIdx.x * 256u + threadIdx.x;
    const float* s; ushort* d; unsigned off;
    if      (i < CV8_N0){ s = x;   d = xb;   off = i; }
    else if (i < CV8_N1){ s = W1;  d = w1b;  off = i - CV8_N0; }
    else if (i < CV8_N2){ s = W2;  d = w2b;  off = i - CV8_N1; }
    else if (i < CV8_N3){ s = Ws1; d = ws1b; off = i - CV8_N2; }
    else                { s = Ws2; d = ws2b; off = i - CV8_N3; }
    const float4* s4 = reinterpret_cast<const float4*>(s) + 2 * (size_t)off;
    float4 a = s4[0];
    float4 b = s4[1];
    short8 o;
    o[0] = (short)f2bf(a.x); o[1] = (short)f2bf(a.y);
    o[2] = (short)f2bf(a.z); o[3] = (short)f2bf(a.w);
    o[4] = (short)f2bf(b.x); o[5] = (short)f2bf(b.y);
    o[6] = (short)f2bf(b.z); o[7] = (short)f2bf(b.w);
    reinterpret_cast<short8*>(d)[off] = o;
}

// one wave per token: fp32 logits -> softmax -> top2
__global__ __launch_bounds__(256) void router_kernel(
    const float* __restrict__ x, const float* __restrict__ wr,
    int* __restrict__ te, float* __restrict__ tg, int* __restrict__ tokarr)
{
    const int token = blockIdx.x * 4 + (threadIdx.x >> 6);
    const int lane  = threadIdx.x & 63;
    const float* xp = x + (size_t)token * DM;
    float s[8];
    #pragma unroll
    for (int e = 0; e < 8; e++) s[e] = 0.f;
    for (int d = lane; d < DM; d += 64){
        float xv = xp[d];
        #pragma unroll
        for (int e = 0; e < 8; e++) s[e] += xv * wr[e * DM + d];
    }
    #pragma unroll
    for (int e = 0; e < 8; e++){
        float v = s[e];
        #pragma unroll
        for (int off = 32; off > 0; off >>= 1) v += __shfl_down(v, off);
        s[e] = v;
    }
    if (lane == 0){
        float m = s[0];
        #pragma unroll
        for (int e = 1; e < 8; e++) m = fmaxf(m, s[e]);
        float p[8]; float sum = 0.f;
        #pragma unroll
        for (int e = 0; e < 8; e++){ p[e] = __expf(s[e] - m); sum += p[e]; }
        float inv = 1.f / sum;
        #pragma unroll
        for (int e = 0; e < 8; e++) p[e] *= inv;
        int i1 = 0; float p1 = p[0];
        #pragma unroll
        for (int e = 1; e < 8; e++) if (p[e] > p1){ p1 = p[e]; i1 = e; }
        int i2 = -1; float p2 = -1.f;
        #pragma unroll
        for (int e = 0; e < 8; e++) if (e != i1 && p[e] > p2){ p2 = p[e]; i2 = e; }
        te[token*2+0] = i1; te[token*2+1] = i2;
        tg[token*2+0] = p1; tg[token*2+1] = p2;
        tokarr[token] = token;      // shared-expert rows = identity
    }
}

// single 256-thread block: counts -> prefix/meta -> scatter routed rows.
// meta layout: [0..8]=counts, [16..24]=rowbase, [32..40]=mtiles
__global__ __launch_bounds__(256) void plan_kernel(
    const int* __restrict__ te, int* __restrict__ tokarr,
    int* __restrict__ rowof, int* __restrict__ meta)
{
    __shared__ int lc[9], lcur[9];
    const int t = threadIdx.x;
    if (t < 9) lc[t] = 0;
    __syncthreads();
    for (int j = t; j < NTOK*2; j += 256) atomicAdd(&lc[te[j]], 1);
    __syncthreads();
    if (t == 0){
        int off = NTOK;
        for (int e = 0; e < 8; e++){
            lcur[e]    = off;
            meta[e]    = lc[e];
            meta[16+e] = off;
            meta[32+e] = (lc[e] + BM - 1) / BM;
            off += lc[e];
        }
        meta[8]    = NTOK;      // shared expert
        meta[16+8] = 0;
        meta[32+8] = NTOK / BM;
    }
    __syncthreads();
    for (int j = t; j < NTOK*2; j += 256){
        int e = te[j];
        int p = atomicAdd(&lcur[e], 1);
        tokarr[p] = j >> 1;
        rowof[j]  = p;
    }
}

// ---- counted-vmcnt ring pipeline (T4) ----------------------------------
// 4 stages x BK=32. Per sub-step: vmcnt(N) -> s_barrier -> issue stage k+3
// -> ds_read 8 frags -> 16 MFMA. Loads stay in flight across 3 phases
// (never drained in steady state). Distinct LDS arrays per stage so alias
// analysis cannot force conservative drains.
// Safety: a buffer re-issued at step k was last read at step k-1; every
// wave's step-(k-1) ds_reads are register-complete (lgkm) before its MFMAs,
// which precede the step-k barrier; issues happen after that barrier.
#define WAIT8 asm volatile("s_waitcnt vmcnt(8)" ::: "memory")
#define WAIT4 asm volatile("s_waitcnt vmcnt(4)" ::: "memory")
#define WAIT0 asm volatile("s_waitcnt vmcnt(0)" ::: "memory")

// stage issue: 4 GLD16/thread (2 A + 2 B), LDS slot s=j*256+t <-> row s>>2,
// phys col-seg s&3 holding logical seg (s&3)^(row&3) (pre-swizzled source).
#define ISSUE4(AsX, BsX, ke) do{ \
    GLD16(ApS0 + (ke), &AsX[(size_t)t * 8]); \
    GLD16(ApS1 + (ke), &AsX[2048 + (size_t)t * 8]); \
    GLD16(BpS0 + (ke), &BsX[(size_t)t * 8]); \
    GLD16(BpS1 + (ke), &BsX[2048 + (size_t)t * 8]); }while(0)

// fragment read: logical seg q=quad -> phys = quad ^ (row&3), row&3 == lane&3
#define COMPUTE32(AsX, BsX) do{ \
    short8 af[4], bfr[4]; \
    _Pragma("unroll") \
    for (int mi = 0; mi < 4; mi++){ \
        int row = wm + mi * 16 + lrow; \
        af[mi] = *reinterpret_cast<const short8*>(&AsX[row * 32 + physq]); } \
    _Pragma("unroll") \
    for (int ni = 0; ni < 4; ni++){ \
        int row = wn + ni * 16 + lrow; \
        bfr[ni] = *reinterpret_cast<const short8*>(&BsX[row * 32 + physq]); } \
    _Pragma("unroll") \
    for (int mi = 0; mi < 4; mi++) \
        _Pragma("unroll") \
        for (int ni = 0; ni < 4; ni++) \
            acc[mi][ni] = __builtin_amdgcn_mfma_f32_16x16x32_bf16(af[mi], bfr[ni], acc[mi][ni], 0, 0, 0); \
    }while(0)

#define STEP(AsC, BsC, AsN, BsN, ke, DOISSUE, WAITM) do{ \
    WAITM; \
    __builtin_amdgcn_s_barrier(); \
    if (DOISSUE) ISSUE4(AsN, BsN, ke); \
    __builtin_amdgcn_sched_barrier(0); \
    COMPUTE32(AsC, BsC); \
    __builtin_amdgcn_sched_barrier(0); \
}while(0)

// MODE 0: H[row] = gelu(Xg @ W1_e^T + b1)   (N=4096=32 nt, K=1024) -> bf16 H
// MODE 1: Y[row] = H @ W2_e^T + b2          (N=1024= 8 nt, K=4096) -> fp32 Y
template<int MODE>
__global__ __launch_bounds__(256) void gemm_kernel(
    const ushort* __restrict__ Abase,
    const ushort* __restrict__ Wb, const ushort* __restrict__ Wsb,
    const float* __restrict__ brout, const float* __restrict__ bsh,
    const int* __restrict__ meta, const int* __restrict__ tokarr,
    ushort* __restrict__ Hout, float* __restrict__ Yout)
{
    const int xcd = blockIdx.x & 7;
    const int q   = blockIdx.x >> 3;
    const int NTG = (MODE == 0) ? 4 : 1;     // nt-columns per expert per XCD

    int e = -1, r = 0, a0 = 0;
    #pragma unroll
    for (int ee = 0; ee < 9; ee++){
        int w = NTG * meta[32 + ee];
        if (e < 0 && q < a0 + w){ e = ee; r = q - a0; }
        a0 += w;
    }
    if (e < 0) return;
    const int mt_e = meta[32 + e];
    int ntg, mti;
    if (MODE == 0){ ntg = r / mt_e; mti = r - ntg * mt_e; }
    else          { ntg = 0;        mti = r; }
    const int nt   = (MODE == 0) ? (xcd + 8 * ntg) : xcd;
    const int cnt  = meta[e];
    const int base = meta[16 + e];

    const int K = (MODE == 0) ? DM : DF;
    const int N = (MODE == 0) ? DF : DM;
    const int ks = K / 32;                   // 32 (MODE0) / 128 (MODE1) sub-steps
    const ushort* Bp  = (e < 8) ? (Wb + (size_t)e * DF * DM) : Wsb;
    const float* bias = (e < 8) ? (brout + e * N) : bsh;

    // 4-stage ring: 4 distinct arrays per operand (8 KB each, 64 KB total)
    __shared__ __align__(16) ushort As0[BM*32], As1[BM*32], As2[BM*32], As3[BM*32];
    __shared__ __align__(16) ushort Bs0[BN*32], Bs1[BN*32], Bs2[BN*32], Bs3[BN*32];

    const int t    = threadIdx.x;
    const int lane = t & 63;
    const int wv   = t >> 6;
    const int wm   = (wv >> 1) * 64;
    const int wn   = (wv & 1) * 64;
    const int lrow = lane & 15;
    const int quad = lane >> 4;
    const int physq = ((quad ^ (lane & 3)) * 8);   // fragment phys col-seg (elems)

    // staging pointers: thread t, load j -> LDS slot s=j*256+t, row rin=s>>2,
    // global col-seg = (s&3)^(rin&3)  (inverse of the read swizzle)
    const int colswz = (((t & 3) ^ ((t >> 2) & 3)) * 8);
    const ushort *ApS0, *ApS1, *BpS0, *BpS1;
    {
        int rin0 = (t >> 2);          // j=0: rows 0..63
        int rin1 = 64 + (t >> 2);     // j=1: rows 64..127
        int p0 = mti * BM + rin0; p0 = (p0 < cnt) ? p0 : (cnt - 1);
        int p1 = mti * BM + rin1; p1 = (p1 < cnt) ? p1 : (cnt - 1);
        if (MODE == 0){
            ApS0 = Abase + (size_t)tokarr[base + p0] * DM + colswz;
            ApS1 = Abase + (size_t)tokarr[base + p1] * DM + colswz;
        } else {
            ApS0 = Abase + (size_t)(base + p0) * DF + colswz;
            ApS1 = Abase + (size_t)(base + p1) * DF + colswz;
        }
        BpS0 = Bp + (size_t)(nt * BN + rin0) * K + colswz;
        BpS1 = Bp + (size_t)(nt * BN + rin1) * K + colswz;
    }

    floatx4 acc[4][4];
    #pragma unroll
    for (int mi = 0; mi < 4; mi++)
        #pragma unroll
        for (int ni = 0; ni < 4; ni++)
            acc[mi][ni] = (floatx4){0.f, 0.f, 0.f, 0.f};

    // prologue: issue stages 0,1,2 (12 loads in flight)
    ISSUE4(As0, Bs0, 0);
    ISSUE4(As1, Bs1, 32);
    ISSUE4(As2, Bs2, 64);

    // main: sub-steps 0..ks-5; each consumes buf k%4, issues stage k+3
    #pragma unroll 1
    for (int k = 0; k + 8 <= ks; k += 4){
        const int ke = (k + 3) * 32;
        STEP(As0, Bs0, As3, Bs3, ke,      true, WAIT8);
        STEP(As1, Bs1, As0, Bs0, ke + 32, true, WAIT8);
        STEP(As2, Bs2, As1, Bs1, ke + 64, true, WAIT8);
        STEP(As3, Bs3, As2, Bs2, ke + 96, true, WAIT8);
    }
    // tail: steps ks-4..ks-1 (bufs 0..3); only ks-4 still issues (stage ks-1)
    STEP(As0, Bs0, As3, Bs3, (ks - 1) * 32, true,  WAIT8);
    STEP(As1, Bs1, As0, Bs0, 0,             false, WAIT8);
    STEP(As2, Bs2, As0, Bs0, 0,             false, WAIT4);
    STEP(As3, Bs3, As0, Bs0, 0,             false, WAIT0);

    // epilogue; C/D: col = lane&15, row = quad*4 + reg  [m89]
    float bv[4];
    #pragma unroll
    for (int ni = 0; ni < 4; ni++) bv[ni] = bias[nt * BN + wn + ni*16 + lrow];

    #pragma unroll
    for (int mi = 0; mi < 4; mi++){
        #pragma unroll
        for (int rg = 0; rg < 4; rg++){
            int s   = wm + mi*16 + quad*4 + rg;
            int pos = mti * BM + s;
            if (pos >= cnt) continue;
            int rr = base + pos;
            if (MODE == 0){
                ushort* hp = Hout + (size_t)rr * DF + nt * BN;
                #pragma unroll
                for (int ni = 0; ni < 4; ni++){
                    float v = acc[mi][ni][rg] + bv[ni];
                    hp[wn + ni*16 + lrow] = f2bf(gelu_tanh(v));
                }
            } else {
                float* yp = Yout + (size_t)rr * DM + nt * BN;
                #pragma unroll
                for (int ni = 0; ni < 4; ni++)
                    yp[wn + ni*16 + lrow] = acc[mi][ni][rg] + bv[ni];
            }
        }
    }
}

// out[t] = SCALE * (Y[t] + g1*Y[r1] + g2*Y[r2])
__global__ __launch_bounds__(256) void combine_kernel(
    const float* __restrict__ Y, const int* __restrict__ rowof,
    const float* __restrict__ tg, float* __restrict__ out)
{
    const int token = blockIdx.x;
    const int d4    = threadIdx.x;
    const float4* Y4 = reinterpret_cast<const float4*>(Y);
    int r1 = rowof[token*2+0], r2 = rowof[token*2+1];
    float g1 = tg[token*2+0],  g2 = tg[token*2+1];
    float4 a = Y4[(size_t)token * 256 + d4];
    float4 b = Y4[(size_t)r1 * 256 + d4];
    float4 c = Y4[(size_t)r2 * 256 + d4];
    float4 o;
    o.x = SCALE_F * (a.x + g1*b.x + g2*c.x);
    o.y = SCALE_F * (a.y + g1*b.y + g2*c.y);
    o.z = SCALE_F * (a.z + g1*b.z + g2*c.z);
    o.w = SCALE_F * (a.w + g1*b.w + g2*c.w);
    reinterpret_cast<float4*>(out)[(size_t)token * 256 + d4] = o;
}

extern "C" void kernel_launch(void* const* d_in, const int* in_sizes, int n_in,
                              void* d_out, int out_size, void* d_ws, size_t ws_size,
                              hipStream_t stream) {
    const float* x   = (const float*)d_in[0];
    const float* wr  = (const float*)d_in[1];
    const float* W1  = (const float*)d_in[2];
    const float* b1  = (const float*)d_in[3];
    const float* W2  = (const float*)d_in[4];
    const float* b2  = (const float*)d_in[5];
    const float* Ws1 = (const float*)d_in[6];
    const float* bs1 = (const float*)d_in[7];
    const float* Ws2 = (const float*)d_in[8];
    const float* bs2 = (const float*)d_in[9];
    float* out = (float*)d_out;

    char* ws = (char*)d_ws;
    size_t off = 0;
    auto wsalloc = [&](size_t bytes) -> char* {
        char* p = ws + off;
        off += (bytes + 255) & ~(size_t)255;
        return p;
    };
    ushort* xb   = (ushort*)wsalloc((size_t)NTOK * DM * 2);
    ushort* w1b  = (ushort*)wsalloc((size_t)8 * DF * DM * 2);
    ushort* w2b  = (ushort*)wsalloc((size_t)8 * DM * DF * 2);
    ushort* ws1b = (ushort*)wsalloc((size_t)DF * DM * 2);
    ushort* ws2b = (ushort*)wsalloc((size_t)DM * DF * 2);
    ushort* H    = (ushort*)wsalloc((size_t)ROWS_TOTAL * DF * 2);
    int*    tokarr = (int*)wsalloc(ROWS_TOTAL * 4);
    int*    rowof  = (int*)wsalloc(NTOK * 2 * 4);
    int*    te     = (int*)wsalloc(NTOK * 2 * 4);
    float*  tg     = (float*)wsalloc(NTOK * 2 * 4);
    int*    meta   = (int*)wsalloc(64 * 4);
    // Y (50.3MB fp32) aliases w1b (67MB): w1b dead after gemm1, Y born in gemm2
    float*  Y = (float*)w1b;

    cvt_all<<<CV8_N4/256, 256, 0, stream>>>(x, W1, W2, Ws1, Ws2,
                                            xb, w1b, w2b, ws1b, ws2b);
    router_kernel<<<NTOK/4, 256, 0, stream>>>(x, wr, te, tg, tokarr);
    plan_kernel<<<1, 256, 0, stream>>>(te, tokarr, rowof, meta);

    // grid = 8 XCD lanes x worst-case per-XCD queue length
    gemm_kernel<0><<<8 * 4 * PMAX, 256, 0, stream>>>(xb, w1b, ws1b, b1, bs1,
        meta, tokarr, H, Y);
    gemm_kernel<1><<<8 * PMAX, 256, 0, stream>>>(H, w2b, ws2b, b2, bs2,
        meta, tokarr, H, Y);

    combine_kernel<<<NTOK, 256, 0, stream>>>(Y, rowof, tg, out);
}